// Round 1
// baseline (504.299 us; speedup 1.0000x reference)
//
#include <hip/hip_runtime.h>

// ---------------------------------------------------------------------------
// GAT 3-layer forward, MI355X (gfx950)
// Strategy: bf16-split (hi+lo) MFMA GEMMs + CSR-by-dst waves for attention.
// ---------------------------------------------------------------------------

typedef __attribute__((ext_vector_type(8))) __bf16 bf16x8;
typedef __attribute__((ext_vector_type(4))) float f32x4;

#define NEG_SLOPE 0.2f

__device__ __forceinline__ unsigned short f2b_rne(float f) {
    unsigned int u = __float_as_uint(f);
    u += 0x7FFFu + ((u >> 16) & 1u);
    return (unsigned short)(u >> 16);
}
__device__ __forceinline__ float b2f(unsigned short s) {
    return __uint_as_float(((unsigned int)s) << 16);
}

// ---- conversion: x [N,256] f32 -> xb [N,512] bf16 (hi || lo) --------------
__global__ __launch_bounds__(256) void k_split_x(const float* __restrict__ in,
                                                 unsigned short* __restrict__ out,
                                                 int n_vec4) {
    int t = blockIdx.x * blockDim.x + threadIdx.x;
    if (t >= n_vec4) return;
    int row = t >> 6;            // 64 float4 per 256-wide row
    int col = (t & 63) * 4;
    float4 v = *(const float4*)&in[(size_t)row * 256 + col];
    unsigned short h0 = f2b_rne(v.x), h1 = f2b_rne(v.y);
    unsigned short h2 = f2b_rne(v.z), h3 = f2b_rne(v.w);
    ushort4 hi = make_ushort4(h0, h1, h2, h3);
    ushort4 lo = make_ushort4(f2b_rne(v.x - b2f(h0)), f2b_rne(v.y - b2f(h1)),
                              f2b_rne(v.z - b2f(h2)), f2b_rne(v.w - b2f(h3)));
    *(ushort4*)&out[(size_t)row * 512 + col] = hi;
    *(ushort4*)&out[(size_t)row * 512 + 256 + col] = lo;
}

// ---- W [256,Nout] f32 -> Wd [512,Nout] bf16 (rows duplicated) -------------
__global__ __launch_bounds__(256) void k_wdup(const float* __restrict__ W,
                                              unsigned short* __restrict__ out,
                                              int total) {
    int t = blockIdx.x * blockDim.x + threadIdx.x;
    if (t >= total) return;
    unsigned short b = f2b_rne(W[t]);
    out[t] = b;
    out[t + total] = b;   // rows 256..511 duplicate rows 0..255
}

// ---- CSR build ------------------------------------------------------------
__global__ __launch_bounds__(256) void k_zero(int* __restrict__ p, int n) {
    int t = blockIdx.x * blockDim.x + threadIdx.x;
    if (t < n) p[t] = 0;
}

__global__ __launch_bounds__(256) void k_count(const int* __restrict__ dst,
                                               int* __restrict__ cnt, int E) {
    int t = blockIdx.x * blockDim.x + threadIdx.x;
    if (t < E) atomicAdd(&cnt[dst[t]], 1);
}

#define SCAN_B 256
__global__ __launch_bounds__(SCAN_B) void k_scan1(const int* __restrict__ cnt,
                                                  int* __restrict__ excl,
                                                  int* __restrict__ bsums, int n) {
    __shared__ int sh[SCAN_B];
    int i = blockIdx.x * SCAN_B + threadIdx.x;
    int v = (i < n) ? cnt[i] : 0;
    sh[threadIdx.x] = v;
    __syncthreads();
    for (int off = 1; off < SCAN_B; off <<= 1) {
        int t = (threadIdx.x >= off) ? sh[threadIdx.x - off] : 0;
        __syncthreads();
        sh[threadIdx.x] += t;
        __syncthreads();
    }
    int incl = sh[threadIdx.x];
    if (i < n) excl[i] = incl - v;
    if (threadIdx.x == SCAN_B - 1) bsums[blockIdx.x] = incl;
}

__global__ __launch_bounds__(SCAN_B) void k_scan2(int* __restrict__ bsums, int nb) {
    __shared__ int sh[SCAN_B];
    int v = (threadIdx.x < nb) ? bsums[threadIdx.x] : 0;
    sh[threadIdx.x] = v;
    __syncthreads();
    for (int off = 1; off < SCAN_B; off <<= 1) {
        int t = (threadIdx.x >= off) ? sh[threadIdx.x - off] : 0;
        __syncthreads();
        sh[threadIdx.x] += t;
        __syncthreads();
    }
    if (threadIdx.x < nb) bsums[threadIdx.x] = sh[threadIdx.x] - v;  // exclusive
}

__global__ __launch_bounds__(256) void k_scan3(const int* __restrict__ excl,
                                               const int* __restrict__ bsums,
                                               int* __restrict__ rowoff,
                                               int* __restrict__ cursor,
                                               int n, int E) {
    int i = blockIdx.x * blockDim.x + threadIdx.x;
    if (i < n) {
        int o = excl[i] + bsums[i >> 8];
        rowoff[i] = o;
        cursor[i] = o;
    }
    if (i == 0) rowoff[n] = E;
}

__global__ __launch_bounds__(256) void k_fill(const int* __restrict__ src,
                                              const int* __restrict__ dst,
                                              int* __restrict__ cursor,
                                              int* __restrict__ csr, int E) {
    int t = blockIdx.x * blockDim.x + threadIdx.x;
    if (t < E) {
        int pos = atomicAdd(&cursor[dst[t]], 1);
        csr[pos] = src[t];
    }
}

// ---- GEMM: C[M,N] f32 = A[M,K] bf16 @ B[K,N] bf16 -------------------------
// 128x64 tile, BK=64, 4 waves each compute 32 rows x 64 cols via 16x16x32 MFMA.
#define BM 128
#define BN 64
#define BK 64
#define LPAD 8   // +8 bf16 => row stride 144 B = 9*16 B (16B-aligned b128 reads)

__global__ __launch_bounds__(256) void k_gemm(const __bf16* __restrict__ A,
                                              const __bf16* __restrict__ B,
                                              float* __restrict__ C,
                                              int M, int N, int K) {
    __shared__ __align__(16) __bf16 As[BM][BK + LPAD];
    __shared__ __align__(16) __bf16 Bs[BN][BK + LPAD];

    int m0 = blockIdx.x * BM;
    int n0 = blockIdx.y * BN;
    int tid = threadIdx.x;
    int lane = tid & 63;
    int w = tid >> 6;

    f32x4 acc[2][4] = {};

    for (int k0 = 0; k0 < K; k0 += BK) {
        // stage A: 128x64 bf16; 8 threads/row, 32 rows/pass, 4 passes
        {
            int tr = tid >> 3;
            int tc = (tid & 7) * 8;
#pragma unroll
            for (int p = 0; p < 4; p++) {
                int row = tr + p * 32;
                int grow = m0 + row;
                if (grow >= M) grow = M - 1;
                *(int4*)&As[row][tc] =
                    *(const int4*)&A[(size_t)grow * K + k0 + tc];
            }
        }
        // stage B transposed: Bs[n][k] <- B[k][n]; 64x64
        {
            int tr = tid >> 3;           // k-row within tile
            int tc = (tid & 7) * 8;      // n base
#pragma unroll
            for (int p = 0; p < 2; p++) {
                int kr = tr + p * 32;
                __bf16 tmp[8];
                *(int4*)tmp = *(const int4*)&B[(size_t)(k0 + kr) * N + n0 + tc];
#pragma unroll
                for (int j = 0; j < 8; j++) Bs[tc + j][kr] = tmp[j];
            }
        }
        __syncthreads();

#pragma unroll
        for (int kc = 0; kc < 2; kc++) {
            int koff = kc * 32 + (lane >> 4) * 8;
            bf16x8 af[2];
#pragma unroll
            for (int mt = 0; mt < 2; mt++)
                af[mt] = *(const bf16x8*)&As[w * 32 + mt * 16 + (lane & 15)][koff];
#pragma unroll
            for (int nt = 0; nt < 4; nt++) {
                bf16x8 bfv = *(const bf16x8*)&Bs[nt * 16 + (lane & 15)][koff];
                acc[0][nt] = __builtin_amdgcn_mfma_f32_16x16x32_bf16(af[0], bfv, acc[0][nt], 0, 0, 0);
                acc[1][nt] = __builtin_amdgcn_mfma_f32_16x16x32_bf16(af[1], bfv, acc[1][nt], 0, 0, 0);
            }
        }
        __syncthreads();
    }

    // epilogue: row = m0 + w*32 + mt*16 + (lane>>4)*4 + r ; col = n0 + nt*16 + (lane&15)
#pragma unroll
    for (int mt = 0; mt < 2; mt++) {
#pragma unroll
        for (int r = 0; r < 4; r++) {
            int row = m0 + w * 32 + mt * 16 + (lane >> 4) * 4 + r;
            if (row < M) {
#pragma unroll
                for (int nt = 0; nt < 4; nt++) {
                    C[(size_t)row * N + n0 + nt * 16 + (lane & 15)] = acc[mt][nt][r];
                }
            }
        }
    }
}

// ---- attention logits: als/ald [N,H] from h [N,H*C] -----------------------
__global__ __launch_bounds__(256) void k_al4(const float* __restrict__ h,
                                             const float* __restrict__ a_s,
                                             const float* __restrict__ a_d,
                                             float* __restrict__ als,
                                             float* __restrict__ ald, int n) {
    int wid = (blockIdx.x * blockDim.x + threadIdx.x) >> 6;
    if (wid >= n) return;
    int lane = threadIdx.x & 63;
    float4 hv = *(const float4*)&h[(size_t)wid * 256 + lane * 4];
    float4 sv = *(const float4*)&a_s[lane * 4];
    float4 dv = *(const float4*)&a_d[lane * 4];
    float ps = hv.x * sv.x + hv.y * sv.y + hv.z * sv.z + hv.w * sv.w;
    float pd = hv.x * dv.x + hv.y * dv.y + hv.z * dv.z + hv.w * dv.w;
#pragma unroll
    for (int off = 8; off >= 1; off >>= 1) {
        ps += __shfl_xor(ps, off, 64);
        pd += __shfl_xor(pd, off, 64);
    }
    if ((lane & 15) == 0) {
        int head = lane >> 4;
        als[wid * 4 + head] = ps;
        ald[wid * 4 + head] = pd;
    }
}

__global__ __launch_bounds__(256) void k_al1(const float* __restrict__ h,
                                             const float* __restrict__ a_s,
                                             const float* __restrict__ a_d,
                                             float* __restrict__ als,
                                             float* __restrict__ ald, int n) {
    int wid = (blockIdx.x * blockDim.x + threadIdx.x) >> 6;
    if (wid >= n) return;
    int lane = threadIdx.x & 63;
    float hv = h[(size_t)wid * 64 + lane];
    float ps = hv * a_s[lane];
    float pd = hv * a_d[lane];
#pragma unroll
    for (int off = 32; off >= 1; off >>= 1) {
        ps += __shfl_xor(ps, off, 64);
        pd += __shfl_xor(pd, off, 64);
    }
    if (lane == 0) {
        als[wid] = ps;
        ald[wid] = pd;
    }
}

// ---- aggregation, H=4 C=64: softmax over in-edges, bias+ELU, bf16-split out
__global__ __launch_bounds__(256) void k_agg4(const float* __restrict__ h,
                                              const float* __restrict__ als,
                                              const float* __restrict__ ald,
                                              const int* __restrict__ rowoff,
                                              const int* __restrict__ csr,
                                              const float* __restrict__ bias,
                                              unsigned short* __restrict__ xout,
                                              int n) {
    int wid = (blockIdx.x * blockDim.x + threadIdx.x) >> 6;
    if (wid >= n) return;
    int lane = threadIdx.x & 63;
    int head = lane >> 4;

    float aldv = ald[wid * 4 + head];
    float e_self = als[wid * 4 + head] + aldv;
    e_self = e_self >= 0.f ? e_self : NEG_SLOPE * e_self;

    int beg = rowoff[wid], end = rowoff[wid + 1];
    float m = e_self;
    for (int i = beg; i < end; ++i) {
        int s = csr[i];
        float e = als[s * 4 + head] + aldv;
        e = e >= 0.f ? e : NEG_SLOPE * e;
        m = fmaxf(m, e);
    }

    float ssum = 0.f;
    float ax = 0.f, ay = 0.f, az = 0.f, aw = 0.f;
    {
        float p = __expf(e_self - m);
        ssum += p;
        float4 hv = *(const float4*)&h[(size_t)wid * 256 + lane * 4];
        ax += p * hv.x; ay += p * hv.y; az += p * hv.z; aw += p * hv.w;
    }
    for (int i = beg; i < end; ++i) {
        int s = csr[i];
        float e = als[s * 4 + head] + aldv;
        e = e >= 0.f ? e : NEG_SLOPE * e;
        float p = __expf(e - m);
        ssum += p;
        float4 hv = *(const float4*)&h[(size_t)s * 256 + lane * 4];
        ax += p * hv.x; ay += p * hv.y; az += p * hv.z; aw += p * hv.w;
    }
    float inv = 1.f / (ssum + 1e-16f);
    float4 bv = *(const float4*)&bias[lane * 4];
    float r0 = ax * inv + bv.x;
    float r1 = ay * inv + bv.y;
    float r2 = az * inv + bv.z;
    float r3 = aw * inv + bv.w;
    // ELU
    r0 = r0 > 0.f ? r0 : expm1f(r0);
    r1 = r1 > 0.f ? r1 : expm1f(r1);
    r2 = r2 > 0.f ? r2 : expm1f(r2);
    r3 = r3 > 0.f ? r3 : expm1f(r3);
    // bf16 hi+lo split store for next GEMM
    unsigned short h0 = f2b_rne(r0), h1 = f2b_rne(r1), h2 = f2b_rne(r2), h3 = f2b_rne(r3);
    ushort4 hi = make_ushort4(h0, h1, h2, h3);
    ushort4 lo = make_ushort4(f2b_rne(r0 - b2f(h0)), f2b_rne(r1 - b2f(h1)),
                              f2b_rne(r2 - b2f(h2)), f2b_rne(r3 - b2f(h3)));
    *(ushort4*)&xout[(size_t)wid * 512 + lane * 4] = hi;
    *(ushort4*)&xout[(size_t)wid * 512 + 256 + lane * 4] = lo;
}

// ---- aggregation, H=1 C=64, final layer: +bias, f32 out -------------------
__global__ __launch_bounds__(256) void k_agg1(const float* __restrict__ h,
                                              const float* __restrict__ als,
                                              const float* __restrict__ ald,
                                              const int* __restrict__ rowoff,
                                              const int* __restrict__ csr,
                                              const float* __restrict__ bias,
                                              float* __restrict__ out, int n) {
    int wid = (blockIdx.x * blockDim.x + threadIdx.x) >> 6;
    if (wid >= n) return;
    int lane = threadIdx.x & 63;

    float aldv = ald[wid];
    float e_self = als[wid] + aldv;
    e_self = e_self >= 0.f ? e_self : NEG_SLOPE * e_self;

    int beg = rowoff[wid], end = rowoff[wid + 1];
    float m = e_self;
    for (int i = beg; i < end; ++i) {
        int s = csr[i];
        float e = als[s] + aldv;
        e = e >= 0.f ? e : NEG_SLOPE * e;
        m = fmaxf(m, e);
    }
    float ssum = 0.f, acc = 0.f;
    {
        float p = __expf(e_self - m);
        ssum += p;
        acc += p * h[(size_t)wid * 64 + lane];
    }
    for (int i = beg; i < end; ++i) {
        int s = csr[i];
        float e = als[s] + aldv;
        e = e >= 0.f ? e : NEG_SLOPE * e;
        float p = __expf(e - m);
        ssum += p;
        acc += p * h[(size_t)s * 64 + lane];
    }
    out[(size_t)wid * 64 + lane] = acc / (ssum + 1e-16f) + bias[lane];
}

// ---------------------------------------------------------------------------
extern "C" void kernel_launch(void* const* d_in, const int* in_sizes, int n_in,
                              void* d_out, int out_size, void* d_ws, size_t ws_size,
                              hipStream_t stream) {
    const float* x   = (const float*)d_in[0];
    const int*   ei  = (const int*)d_in[1];
    const float* W1  = (const float*)d_in[2];
    const float* as1 = (const float*)d_in[3];
    const float* ad1 = (const float*)d_in[4];
    const float* b1  = (const float*)d_in[5];
    const float* W2  = (const float*)d_in[6];
    const float* as2 = (const float*)d_in[7];
    const float* ad2 = (const float*)d_in[8];
    const float* b2  = (const float*)d_in[9];
    const float* W3  = (const float*)d_in[10];
    const float* as3 = (const float*)d_in[11];
    const float* ad3 = (const float*)d_in[12];
    const float* b3  = (const float*)d_in[13];

    const int N = in_sizes[0] / 256;   // 50000
    const int E = in_sizes[1] / 2;     // 320000

    // workspace carve-up (256B aligned)
    size_t off = 0;
    auto alloc = [&](size_t bytes) -> void* {
        void* p = (char*)d_ws + off;
        off += (bytes + 255) & ~(size_t)255;
        return p;
    };
    unsigned short* xb  = (unsigned short*)alloc((size_t)N * 512 * 2);
    unsigned short* W1d = (unsigned short*)alloc((size_t)512 * 256 * 2);
    unsigned short* W2d = (unsigned short*)alloc((size_t)512 * 256 * 2);
    unsigned short* W3d = (unsigned short*)alloc((size_t)512 * 64 * 2);
    float* h    = (float*)alloc((size_t)N * 256 * 4);
    float* als  = (float*)alloc((size_t)N * 4 * 4);
    float* ald  = (float*)alloc((size_t)N * 4 * 4);
    int* cnt    = (int*)alloc((size_t)N * 4);
    int* rowoff = (int*)alloc((size_t)(N + 1) * 4);
    int* excl   = (int*)alloc((size_t)N * 4);
    int* bsums  = (int*)alloc((size_t)SCAN_B * 4);
    int* cursor = (int*)alloc((size_t)N * 4);
    int* csr    = (int*)alloc((size_t)E * 4);

    const int T = 256;
    const int nbk = (N + SCAN_B - 1) / SCAN_B;       // 196
    const int node_wave_blocks = (N * 64 + T - 1) / T;  // 12500
    const int mtiles = (N + BM - 1) / BM;            // 391

    // conversions
    k_split_x<<<dim3((N * 64 + T - 1) / T), T, 0, stream>>>(x, xb, N * 64);
    k_wdup<<<dim3((256 * 256 + T - 1) / T), T, 0, stream>>>(W1, W1d, 256 * 256);
    k_wdup<<<dim3((256 * 256 + T - 1) / T), T, 0, stream>>>(W2, W2d, 256 * 256);
    k_wdup<<<dim3((256 * 64 + T - 1) / T), T, 0, stream>>>(W3, W3d, 256 * 64);

    // CSR build (dst-grouped); self-loops handled analytically in agg kernels
    k_zero<<<dim3((N + T - 1) / T), T, 0, stream>>>(cnt, N);
    k_count<<<dim3((E + T - 1) / T), T, 0, stream>>>(ei + E, cnt, E);
    k_scan1<<<dim3(nbk), SCAN_B, 0, stream>>>(cnt, excl, bsums, N);
    k_scan2<<<dim3(1), SCAN_B, 0, stream>>>(bsums, nbk);
    k_scan3<<<dim3(nbk), T, 0, stream>>>(excl, bsums, rowoff, cursor, N, E);
    k_fill<<<dim3((E + T - 1) / T), T, 0, stream>>>(ei, ei + E, cursor, csr, E);

    // layer 1
    k_gemm<<<dim3(mtiles, 4), T, 0, stream>>>((const __bf16*)xb, (const __bf16*)W1d, h, N, 256, 512);
    k_al4<<<dim3(node_wave_blocks), T, 0, stream>>>(h, as1, ad1, als, ald, N);
    k_agg4<<<dim3(node_wave_blocks), T, 0, stream>>>(h, als, ald, rowoff, csr, b1, xb, N);

    // layer 2
    k_gemm<<<dim3(mtiles, 4), T, 0, stream>>>((const __bf16*)xb, (const __bf16*)W2d, h, N, 256, 512);
    k_al4<<<dim3(node_wave_blocks), T, 0, stream>>>(h, as2, ad2, als, ald, N);
    k_agg4<<<dim3(node_wave_blocks), T, 0, stream>>>(h, als, ald, rowoff, csr, b2, xb, N);

    // layer 3 (H=1, C=64)
    k_gemm<<<dim3(mtiles, 1), T, 0, stream>>>((const __bf16*)xb, (const __bf16*)W3d, h, N, 64, 512);
    k_al1<<<dim3(node_wave_blocks), T, 0, stream>>>(h, as3, ad3, als, ald, N);
    k_agg1<<<dim3(node_wave_blocks), T, 0, stream>>>(h, als, ald, rowoff, csr, b3, (float*)d_out, N);
}

// Round 2
// 359.421 us; speedup vs baseline: 1.4031x; 1.4031x over previous
//
#include <hip/hip_runtime.h>

// ---------------------------------------------------------------------------
// GAT 3-layer forward, MI355X (gfx950)
// R2: global_load_lds GEMM (XOR-swizzled LDS, W pre-transposed), fused
//     als/ald epilogue, f16 h storage, single-pass softmax aggregation.
// ---------------------------------------------------------------------------

typedef __attribute__((ext_vector_type(8))) __bf16 bf16x8;
typedef __attribute__((ext_vector_type(4))) float f32x4;

#define NEG_SLOPE 0.2f

__device__ __forceinline__ unsigned short f2b_rne(float f) {
    unsigned int u = __float_as_uint(f);
    u += 0x7FFFu + ((u >> 16) & 1u);
    return (unsigned short)(u >> 16);
}
__device__ __forceinline__ float b2f(unsigned short s) {
    return __uint_as_float(((unsigned int)s) << 16);
}
__device__ __forceinline__ float h2f(unsigned short s) {
    _Float16 h;
    __builtin_memcpy(&h, &s, 2);
    return (float)h;
}
__device__ __forceinline__ unsigned short f2h(float f) {
    _Float16 h = (_Float16)f;
    unsigned short s;
    __builtin_memcpy(&s, &h, 2);
    return s;
}

// ---- conversion: x [N,256] f32 -> xb [N,512] bf16 (hi || lo) --------------
__global__ __launch_bounds__(256) void k_split_x(const float* __restrict__ in,
                                                 unsigned short* __restrict__ out,
                                                 int n_vec4) {
    int t = blockIdx.x * blockDim.x + threadIdx.x;
    if (t >= n_vec4) return;
    int row = t >> 6;
    int col = (t & 63) * 4;
    float4 v = *(const float4*)&in[(size_t)row * 256 + col];
    unsigned short h0 = f2b_rne(v.x), h1 = f2b_rne(v.y);
    unsigned short h2 = f2b_rne(v.z), h3 = f2b_rne(v.w);
    ushort4 hi = make_ushort4(h0, h1, h2, h3);
    ushort4 lo = make_ushort4(f2b_rne(v.x - b2f(h0)), f2b_rne(v.y - b2f(h1)),
                              f2b_rne(v.z - b2f(h2)), f2b_rne(v.w - b2f(h3)));
    *(ushort4*)&out[(size_t)row * 512 + col] = hi;
    *(ushort4*)&out[(size_t)row * 512 + 256 + col] = lo;
}

// ---- W [256,Nout] f32 -> Wt [Nout,512] bf16 transposed, K duplicated ------
__global__ __launch_bounds__(256) void k_wdup_t(const float* __restrict__ W,
                                                unsigned short* __restrict__ Wt,
                                                int Nout, int total) {
    int t = blockIdx.x * blockDim.x + threadIdx.x;
    if (t >= total) return;
    int k = t / Nout;
    int n = t - k * Nout;
    unsigned short b = f2b_rne(W[t]);
    size_t base = (size_t)n * 512 + k;
    Wt[base] = b;
    Wt[base + 256] = b;
}

// ---- CSR build ------------------------------------------------------------
__global__ __launch_bounds__(256) void k_zero(int* __restrict__ p, int n) {
    int t = blockIdx.x * blockDim.x + threadIdx.x;
    if (t < n) p[t] = 0;
}

__global__ __launch_bounds__(256) void k_count(const int* __restrict__ dst,
                                               int* __restrict__ cnt, int E) {
    int t = blockIdx.x * blockDim.x + threadIdx.x;
    if (t < E) atomicAdd(&cnt[dst[t]], 1);
}

#define SCAN_B 256
__global__ __launch_bounds__(SCAN_B) void k_scan1(const int* __restrict__ cnt,
                                                  int* __restrict__ excl,
                                                  int* __restrict__ bsums, int n) {
    __shared__ int sh[SCAN_B];
    int i = blockIdx.x * SCAN_B + threadIdx.x;
    int v = (i < n) ? cnt[i] : 0;
    sh[threadIdx.x] = v;
    __syncthreads();
    for (int off = 1; off < SCAN_B; off <<= 1) {
        int t = (threadIdx.x >= off) ? sh[threadIdx.x - off] : 0;
        __syncthreads();
        sh[threadIdx.x] += t;
        __syncthreads();
    }
    int incl = sh[threadIdx.x];
    if (i < n) excl[i] = incl - v;
    if (threadIdx.x == SCAN_B - 1) bsums[blockIdx.x] = incl;
}

__global__ __launch_bounds__(SCAN_B) void k_scan2(int* __restrict__ bsums, int nb) {
    __shared__ int sh[SCAN_B];
    int v = (threadIdx.x < nb) ? bsums[threadIdx.x] : 0;
    sh[threadIdx.x] = v;
    __syncthreads();
    for (int off = 1; off < SCAN_B; off <<= 1) {
        int t = (threadIdx.x >= off) ? sh[threadIdx.x - off] : 0;
        __syncthreads();
        sh[threadIdx.x] += t;
        __syncthreads();
    }
    if (threadIdx.x < nb) bsums[threadIdx.x] = sh[threadIdx.x] - v;
}

__global__ __launch_bounds__(256) void k_scan3(const int* __restrict__ excl,
                                               const int* __restrict__ bsums,
                                               int* __restrict__ rowoff,
                                               int* __restrict__ cursor,
                                               int n, int E) {
    int i = blockIdx.x * blockDim.x + threadIdx.x;
    if (i < n) {
        int o = excl[i] + bsums[i >> 8];
        rowoff[i] = o;
        cursor[i] = o;
    }
    if (i == 0) rowoff[n] = E;
}

__global__ __launch_bounds__(256) void k_fill(const int* __restrict__ src,
                                              const int* __restrict__ dst,
                                              int* __restrict__ cursor,
                                              int* __restrict__ csr, int E) {
    int t = blockIdx.x * blockDim.x + threadIdx.x;
    if (t < E) {
        int pos = atomicAdd(&cursor[dst[t]], 1);
        csr[pos] = src[t];
    }
}

// ---- GEMM: h16[M,N] f16 = A[M,K]bf16 @ Bt[N,K]bf16^T, fused als/ald -------
// 128 x BN tile, BK=64, 4 waves, 16x16x32 MFMA, global_load_lds + XOR swizzle.
template <int BN>
__global__ __launch_bounds__(256) void k_gemm(const __bf16* __restrict__ A,
                                              const __bf16* __restrict__ Bt,
                                              unsigned short* __restrict__ h16,
                                              float* __restrict__ als,
                                              float* __restrict__ ald,
                                              const float* __restrict__ a_s,
                                              const float* __restrict__ a_d,
                                              int M, int N, int K, int H) {
    constexpr int NT = BN / 16;   // n-tiles per block
    constexpr int HB = BN / 64;   // heads per block
    __shared__ __align__(16) __bf16 As[128][64];
    __shared__ __align__(16) __bf16 Bs[BN][64];

    const int tid = threadIdx.x;
    const int lane = tid & 63;
    const int w = tid >> 6;
    const int i = lane & 15;
    const int quad = lane >> 4;
    const int m0 = blockIdx.x * 128;
    const int n0 = blockIdx.y * BN;

    const int l8 = lane >> 3;   // row within 8-row staging group
    const int c8 = lane & 7;    // lds chunk this lane fills
    const int swz = c8 ^ l8;    // swizzled global chunk

    f32x4 acc[2][NT] = {};

    for (int k0 = 0; k0 < K; k0 += 64) {
        // A: 128 rows x 64 bf16, 4 insts/wave, 1 KB each
#pragma unroll
        for (int p = 0; p < 4; p++) {
            int row0 = (w * 4 + p) * 8;
            int grow = m0 + row0 + l8;
            if (grow >= M) grow = M - 1;
            const __bf16* gp = A + (size_t)grow * K + k0 + swz * 8;
            __builtin_amdgcn_global_load_lds(
                (const __attribute__((address_space(1))) void*)gp,
                (__attribute__((address_space(3))) void*)&As[row0][0], 16, 0, 0);
        }
        // B: BN rows x 64 bf16
#pragma unroll
        for (int p = 0; p < BN / 32; p++) {
            int row0 = (w * (BN / 32) + p) * 8;
            int nrow = n0 + row0 + l8;
            const __bf16* gp = Bt + (size_t)nrow * K + k0 + swz * 8;
            __builtin_amdgcn_global_load_lds(
                (const __attribute__((address_space(1))) void*)gp,
                (__attribute__((address_space(3))) void*)&Bs[row0][0], 16, 0, 0);
        }
        __syncthreads();

#pragma unroll
        for (int kc = 0; kc < 2; kc++) {
            const int cg = ((kc * 4 + quad) ^ (i & 7)) * 8;  // swizzled read chunk
            bf16x8 af[2];
#pragma unroll
            for (int mt = 0; mt < 2; mt++)
                af[mt] = *(const bf16x8*)&As[w * 32 + mt * 16 + i][cg];
#pragma unroll
            for (int nt = 0; nt < NT; nt++) {
                bf16x8 bfv = *(const bf16x8*)&Bs[nt * 16 + i][cg];
                acc[0][nt] = __builtin_amdgcn_mfma_f32_16x16x32_bf16(af[0], bfv, acc[0][nt], 0, 0, 0);
                acc[1][nt] = __builtin_amdgcn_mfma_f32_16x16x32_bf16(af[1], bfv, acc[1][nt], 0, 0, 0);
            }
        }
        __syncthreads();
    }

    // epilogue: C/D map col=lane&15, row=(lane>>4)*4+reg (m89-verified)
    float asv[NT], adv[NT];
#pragma unroll
    for (int nt = 0; nt < NT; nt++) {
        int head = blockIdx.y * HB + nt / 4;
        int cih = (nt & 3) * 16 + i;
        asv[nt] = a_s[head * 64 + cih];
        adv[nt] = a_d[head * 64 + cih];
    }

#pragma unroll
    for (int mt = 0; mt < 2; mt++) {
#pragma unroll
        for (int r = 0; r < 4; r++) {
            int row = m0 + w * 32 + mt * 16 + quad * 4 + r;
            bool ok = row < M;
#pragma unroll
            for (int nt = 0; nt < NT; nt++) {
                if (ok) h16[(size_t)row * N + n0 + nt * 16 + i] = f2h(acc[mt][nt][r]);
            }
#pragma unroll
            for (int g = 0; g < HB; g++) {
                float ps = 0.f, pd = 0.f;
#pragma unroll
                for (int j = 0; j < 4; j++) {
                    float v = acc[mt][g * 4 + j][r];
                    ps += v * asv[g * 4 + j];
                    pd += v * adv[g * 4 + j];
                }
#pragma unroll
                for (int off = 1; off <= 8; off <<= 1) {
                    ps += __shfl_xor(ps, off, 64);
                    pd += __shfl_xor(pd, off, 64);
                }
                if (ok && i == 0) {
                    int head = blockIdx.y * HB + g;
                    als[(size_t)row * H + head] = ps;
                    ald[(size_t)row * H + head] = pd;
                }
            }
        }
    }
}

// ---- aggregation, H=4 C=64: single-pass softmax, bias+ELU, bf16-split out -
__global__ __launch_bounds__(256) void k_agg4(const unsigned short* __restrict__ h16,
                                              const float* __restrict__ als,
                                              const float* __restrict__ ald,
                                              const int* __restrict__ rowoff,
                                              const int* __restrict__ csr,
                                              const float* __restrict__ bias,
                                              unsigned short* __restrict__ xout,
                                              int n) {
    int wid = (blockIdx.x * blockDim.x + threadIdx.x) >> 6;
    if (wid >= n) return;
    int lane = threadIdx.x & 63;
    int head = lane >> 4;

    float aldv = ald[wid * 4 + head];
    float e = als[wid * 4 + head] + aldv;
    e = e >= 0.f ? e : NEG_SLOPE * e;
    float p = __expf(fminf(e, 60.f));
    float ssum = p;
    float a0, a1, a2, a3;
    {
        ushort4 hv = *(const ushort4*)&h16[(size_t)wid * 256 + lane * 4];
        a0 = p * h2f(hv.x); a1 = p * h2f(hv.y); a2 = p * h2f(hv.z); a3 = p * h2f(hv.w);
    }

    int beg = rowoff[wid], end = rowoff[wid + 1];
    int idx = beg;
    for (; idx + 1 < end; idx += 2) {
        int s0 = csr[idx], s1 = csr[idx + 1];
        float e0 = als[s0 * 4 + head] + aldv;
        float e1 = als[s1 * 4 + head] + aldv;
        e0 = e0 >= 0.f ? e0 : NEG_SLOPE * e0;
        e1 = e1 >= 0.f ? e1 : NEG_SLOPE * e1;
        ushort4 v0 = *(const ushort4*)&h16[(size_t)s0 * 256 + lane * 4];
        ushort4 v1 = *(const ushort4*)&h16[(size_t)s1 * 256 + lane * 4];
        float p0 = __expf(fminf(e0, 60.f));
        float p1 = __expf(fminf(e1, 60.f));
        ssum += p0 + p1;
        a0 += p0 * h2f(v0.x) + p1 * h2f(v1.x);
        a1 += p0 * h2f(v0.y) + p1 * h2f(v1.y);
        a2 += p0 * h2f(v0.z) + p1 * h2f(v1.z);
        a3 += p0 * h2f(v0.w) + p1 * h2f(v1.w);
    }
    if (idx < end) {
        int s0 = csr[idx];
        float e0 = als[s0 * 4 + head] + aldv;
        e0 = e0 >= 0.f ? e0 : NEG_SLOPE * e0;
        float p0 = __expf(fminf(e0, 60.f));
        ushort4 v0 = *(const ushort4*)&h16[(size_t)s0 * 256 + lane * 4];
        ssum += p0;
        a0 += p0 * h2f(v0.x); a1 += p0 * h2f(v0.y);
        a2 += p0 * h2f(v0.z); a3 += p0 * h2f(v0.w);
    }

    float inv = 1.f / (ssum + 1e-16f);
    float4 bv = *(const float4*)&bias[lane * 4];
    float r0 = a0 * inv + bv.x;
    float r1 = a1 * inv + bv.y;
    float r2 = a2 * inv + bv.z;
    float r3 = a3 * inv + bv.w;
    r0 = r0 > 0.f ? r0 : expm1f(r0);
    r1 = r1 > 0.f ? r1 : expm1f(r1);
    r2 = r2 > 0.f ? r2 : expm1f(r2);
    r3 = r3 > 0.f ? r3 : expm1f(r3);
    unsigned short h0 = f2b_rne(r0), h1 = f2b_rne(r1), h2 = f2b_rne(r2), h3 = f2b_rne(r3);
    ushort4 hi = make_ushort4(h0, h1, h2, h3);
    ushort4 lo = make_ushort4(f2b_rne(r0 - b2f(h0)), f2b_rne(r1 - b2f(h1)),
                              f2b_rne(r2 - b2f(h2)), f2b_rne(r3 - b2f(h3)));
    *(ushort4*)&xout[(size_t)wid * 512 + lane * 4] = hi;
    *(ushort4*)&xout[(size_t)wid * 512 + 256 + lane * 4] = lo;
}

// ---- aggregation, H=1 C=64, final layer: +bias, f32 out -------------------
__global__ __launch_bounds__(256) void k_agg1(const unsigned short* __restrict__ h16,
                                              const float* __restrict__ als,
                                              const float* __restrict__ ald,
                                              const int* __restrict__ rowoff,
                                              const int* __restrict__ csr,
                                              const float* __restrict__ bias,
                                              float* __restrict__ out, int n) {
    int wid = (blockIdx.x * blockDim.x + threadIdx.x) >> 6;
    if (wid >= n) return;
    int lane = threadIdx.x & 63;

    float aldv = ald[wid];
    float e = als[wid] + aldv;
    e = e >= 0.f ? e : NEG_SLOPE * e;
    float p = __expf(fminf(e, 60.f));
    float ssum = p;
    float acc = p * h2f(h16[(size_t)wid * 64 + lane]);

    int beg = rowoff[wid], end = rowoff[wid + 1];
    int idx = beg;
    for (; idx + 1 < end; idx += 2) {
        int s0 = csr[idx], s1 = csr[idx + 1];
        float e0 = als[s0] + aldv;
        float e1 = als[s1] + aldv;
        e0 = e0 >= 0.f ? e0 : NEG_SLOPE * e0;
        e1 = e1 >= 0.f ? e1 : NEG_SLOPE * e1;
        unsigned short v0 = h16[(size_t)s0 * 64 + lane];
        unsigned short v1 = h16[(size_t)s1 * 64 + lane];
        float p0 = __expf(fminf(e0, 60.f));
        float p1 = __expf(fminf(e1, 60.f));
        ssum += p0 + p1;
        acc += p0 * h2f(v0) + p1 * h2f(v1);
    }
    if (idx < end) {
        int s0 = csr[idx];
        float e0 = als[s0] + aldv;
        e0 = e0 >= 0.f ? e0 : NEG_SLOPE * e0;
        float p0 = __expf(fminf(e0, 60.f));
        ssum += p0;
        acc += p0 * h2f(h16[(size_t)s0 * 64 + lane]);
    }
    out[(size_t)wid * 64 + lane] = acc / (ssum + 1e-16f) + bias[lane];
}

// ---------------------------------------------------------------------------
extern "C" void kernel_launch(void* const* d_in, const int* in_sizes, int n_in,
                              void* d_out, int out_size, void* d_ws, size_t ws_size,
                              hipStream_t stream) {
    const float* x   = (const float*)d_in[0];
    const int*   ei  = (const int*)d_in[1];
    const float* W1  = (const float*)d_in[2];
    const float* as1 = (const float*)d_in[3];
    const float* ad1 = (const float*)d_in[4];
    const float* b1  = (const float*)d_in[5];
    const float* W2  = (const float*)d_in[6];
    const float* as2 = (const float*)d_in[7];
    const float* ad2 = (const float*)d_in[8];
    const float* b2  = (const float*)d_in[9];
    const float* W3  = (const float*)d_in[10];
    const float* as3 = (const float*)d_in[11];
    const float* ad3 = (const float*)d_in[12];
    const float* b3  = (const float*)d_in[13];

    const int N = in_sizes[0] / 256;   // 50000
    const int E = in_sizes[1] / 2;     // 320000

    size_t off = 0;
    auto alloc = [&](size_t bytes) -> void* {
        void* p = (char*)d_ws + off;
        off += (bytes + 255) & ~(size_t)255;
        return p;
    };
    unsigned short* xb  = (unsigned short*)alloc((size_t)N * 512 * 2);
    unsigned short* W1t = (unsigned short*)alloc((size_t)256 * 512 * 2);
    unsigned short* W2t = (unsigned short*)alloc((size_t)256 * 512 * 2);
    unsigned short* W3t = (unsigned short*)alloc((size_t)64 * 512 * 2);
    unsigned short* h16 = (unsigned short*)alloc((size_t)N * 256 * 2);
    float* als  = (float*)alloc((size_t)N * 4 * 4);
    float* ald  = (float*)alloc((size_t)N * 4 * 4);
    int* cnt    = (int*)alloc((size_t)N * 4);
    int* rowoff = (int*)alloc((size_t)(N + 1) * 4);
    int* excl   = (int*)alloc((size_t)N * 4);
    int* bsums  = (int*)alloc((size_t)SCAN_B * 4);
    int* cursor = (int*)alloc((size_t)N * 4);
    int* csr    = (int*)alloc((size_t)E * 4);

    const int T = 256;
    const int nbk = (N + SCAN_B - 1) / SCAN_B;
    const int node_wave_blocks = (N * 64 + T - 1) / T;
    const int mtiles = (N + 127) / 128;

    // conversions
    k_split_x<<<dim3((N * 64 + T - 1) / T), T, 0, stream>>>(x, xb, N * 64);
    k_wdup_t<<<dim3((256 * 256 + T - 1) / T), T, 0, stream>>>(W1, W1t, 256, 256 * 256);
    k_wdup_t<<<dim3((256 * 256 + T - 1) / T), T, 0, stream>>>(W2, W2t, 256, 256 * 256);
    k_wdup_t<<<dim3((256 * 64 + T - 1) / T), T, 0, stream>>>(W3, W3t, 64, 256 * 64);

    // CSR build (dst-grouped); self-loop handled analytically in agg kernels
    k_zero<<<dim3((N + T - 1) / T), T, 0, stream>>>(cnt, N);
    k_count<<<dim3((E + T - 1) / T), T, 0, stream>>>(ei + E, cnt, E);
    k_scan1<<<dim3(nbk), SCAN_B, 0, stream>>>(cnt, excl, bsums, N);
    k_scan2<<<dim3(1), SCAN_B, 0, stream>>>(bsums, nbk);
    k_scan3<<<dim3(nbk), T, 0, stream>>>(excl, bsums, rowoff, cursor, N, E);
    k_fill<<<dim3((E + T - 1) / T), T, 0, stream>>>(ei, ei + E, cursor, csr, E);

    // layer 1
    k_gemm<128><<<dim3(mtiles, 2), T, 0, stream>>>((const __bf16*)xb, (const __bf16*)W1t,
                                                   h16, als, ald, as1, ad1, N, 256, 512, 4);
    k_agg4<<<dim3(node_wave_blocks), T, 0, stream>>>(h16, als, ald, rowoff, csr, b1, xb, N);

    // layer 2
    k_gemm<128><<<dim3(mtiles, 2), T, 0, stream>>>((const __bf16*)xb, (const __bf16*)W2t,
                                                   h16, als, ald, as2, ad2, N, 256, 512, 4);
    k_agg4<<<dim3(node_wave_blocks), T, 0, stream>>>(h16, als, ald, rowoff, csr, b2, xb, N);

    // layer 3 (H=1, C=64)
    k_gemm<64><<<dim3(mtiles, 1), T, 0, stream>>>((const __bf16*)xb, (const __bf16*)W3t,
                                                  h16, als, ald, as3, ad3, N, 64, 512, 1);
    k_agg1<<<dim3(node_wave_blocks), T, 0, stream>>>(h16, als, ald, rowoff, csr, b3,
                                                     (float*)d_out, N);
}